// Round 3
// baseline (251.201 us; speedup 1.0000x reference)
//
#include <hip/hip_runtime.h>
#include <hip/hip_bf16.h>

#define BATCH 32
#define WW 900
#define CCH 256
#define PVAL 450
#define KHALF 128     // K columns per block (K-split x2)
#define MSTRIP 128    // M rows per block
#define NCHUNK 64     // B rows staged per chunk
#define NCHUNKS 15    // 15*64 = 960 >= 900

typedef __bf16 bf16x8 __attribute__((ext_vector_type(8)));
typedef float f32x4 __attribute__((ext_vector_type(4)));

// ---------------- norm pass 1: partial sums of squares ----------------
// grid = 256 blocks: which(2) x b(32) x seg(4); block = 256 threads (c)
// ws layout: sums[64][4][256] floats, then inv[64][256] at float offset 65536
__global__ void nc_norm_partial(const float* __restrict__ x1,
                                const float* __restrict__ x2,
                                float* __restrict__ sums) {
    int blk = blockIdx.x;
    int seg = blk & 3;
    int b = (blk >> 2) & 31;
    int which = blk >> 7;
    const float* x = which ? x2 : x1;
    int c = threadIdx.x;
    const float* p = x + ((size_t)b * WW + seg * 225) * CCH + c;
    float s = 0.f;
    #pragma unroll 8
    for (int w = 0; w < 225; ++w) {
        float v = p[(size_t)w * CCH];
        s = fmaf(v, v, s);
    }
    sums[(((which << 5) | b) * 4 + seg) * CCH + c] = s;
}

// ---------------- norm pass 2: inv = rsqrt(max(sum, eps)) ----------------
__global__ void nc_norm_finalize(float* __restrict__ ws) {
    int i = blockIdx.x * 256 + threadIdx.x;   // [0, 64*256)
    int c = i & 255;
    int wb = i >> 8;                          // which*32 + b
    const float* s = ws + (size_t)wb * 4 * CCH + c;
    float t = (s[0] + s[CCH]) + (s[2 * CCH] + s[3 * CCH]);
    ws[65536 + i] = rsqrtf(fmaxf(t, 1e-12f));
}

// ---------------- main: per-(batch, m-strip, k-half) GEMM + diagonal reduce ----------------
// grid = 512: b = blockIdx&31 (XCD locality), strip = (blockIdx>>5)&7, khalf = blockIdx>>8
// 4 waves = 4 m-slices of 32 rows. B chunks (64 rows x 128 k) double-buffered in LDS.
__global__ __launch_bounds__(256, 2)
void nc_corr(const float* __restrict__ x1,
             const float* __restrict__ x2,
             const float* __restrict__ ws,
             float* __restrict__ out) {
    __shared__ __bf16 Bbuf[2][NCHUNK * KHALF];   // 2 x 16 KB
    __shared__ float partial[WW];                // 3.6 KB

    const int tid = threadIdx.x;
    const int b = blockIdx.x & 31;
    const int strip = (blockIdx.x >> 5) & 7;
    const int kh = blockIdx.x >> 8;
    const int m0 = strip * MSTRIP;
    const int k0 = kh * KHALF;

    const float* __restrict__ inv1 = ws + 65536 + b * CCH + k0;
    const float* __restrict__ inv2 = ws + 65536 + (BATCH + b) * CCH + k0;
    const float* __restrict__ x1b = x1 + (size_t)b * WW * CCH + k0;
    const float* __restrict__ x2b = x2 + (size_t)b * WW * CCH + k0;

    for (int i = tid; i < WW; i += 256) partial[i] = 0.f;

    const int lane = tid & 63;
    const int wave = tid >> 6;     // m-slice: rows m0 + wave*32 .. +31
    const int fr = lane & 15;
    const int fq = lane >> 4;

    // ---- A fragments: direct global -> registers (normalized, bf16) ----
    // af[mt][kk]: row m0+wave*32+mt*16+fr, cols k0 + kk*32+fq*8 .. +8
    bf16x8 af[2][4];
    #pragma unroll
    for (int mt = 0; mt < 2; ++mt) {
        const int row = m0 + wave * 32 + mt * 16 + fr;
        const float* src = x1b + (size_t)row * CCH;
        #pragma unroll
        for (int kk = 0; kk < 4; ++kk) {
            const int c0 = kk * 32 + fq * 8;
            bf16x8 v;
            if (row < WW) {
                float4 f0 = *(const float4*)(src + c0);
                float4 f1 = *(const float4*)(src + c0 + 4);
                float4 i0 = *(const float4*)(inv1 + c0);
                float4 i1 = *(const float4*)(inv1 + c0 + 4);
                v[0] = (__bf16)(f0.x * i0.x); v[1] = (__bf16)(f0.y * i0.y);
                v[2] = (__bf16)(f0.z * i0.z); v[3] = (__bf16)(f0.w * i0.w);
                v[4] = (__bf16)(f1.x * i1.x); v[5] = (__bf16)(f1.y * i1.y);
                v[6] = (__bf16)(f1.z * i1.z); v[7] = (__bf16)(f1.w * i1.w);
            } else {
                #pragma unroll
                for (int e = 0; e < 8; ++e) v[e] = (__bf16)0.f;
            }
            af[mt][kk] = v;
        }
    }

    // ---- B staging: thread owns row = tid>>2, 32 cols at (tid&3)*32 ----
    const int srow = tid >> 2;          // 0..63
    const int scg = tid & 3;            // col group (32 floats)
    float4 iv[8];
    #pragma unroll
    for (int q = 0; q < 8; ++q) iv[q] = *(const float4*)(inv2 + scg * 32 + q * 4);

    float4 st[8];   // in-flight fp32 (32 floats)

    auto loadB = [&](int chunk) {
        const int row = chunk * NCHUNK + srow;
        if (row < WW) {
            const float* s = x2b + (size_t)row * CCH + scg * 32;
            #pragma unroll
            for (int q = 0; q < 8; ++q) st[q] = *(const float4*)(s + q * 4);
        } else {
            #pragma unroll
            for (int q = 0; q < 8; ++q) st[q] = make_float4(0.f, 0.f, 0.f, 0.f);
        }
    };
    // LDS row = 128 bf16 = 256B = 16 granules of 16B; granule g stored at g^(row&7)
    auto writeB = [&](int buf) {
        #pragma unroll
        for (int u = 0; u < 4; ++u) {   // 4 granules: 8 bf16 each
            bf16x8 v;
            float4 a = st[2 * u], bb = st[2 * u + 1];
            float4 ia = iv[2 * u], ib = iv[2 * u + 1];
            v[0] = (__bf16)(a.x * ia.x);  v[1] = (__bf16)(a.y * ia.y);
            v[2] = (__bf16)(a.z * ia.z);  v[3] = (__bf16)(a.w * ia.w);
            v[4] = (__bf16)(bb.x * ib.x); v[5] = (__bf16)(bb.y * ib.y);
            v[6] = (__bf16)(bb.z * ib.z); v[7] = (__bf16)(bb.w * ib.w);
            const int g = (scg * 4 + u) ^ (srow & 7);
            *(bf16x8*)(&Bbuf[buf][srow * KHALF + g * 8]) = v;
        }
    };

    loadB(0);
    writeB(0);
    __syncthreads();   // B chunk 0 staged, partial zeroed

    int cur = 0;
    for (int chunk = 0; chunk < NCHUNKS; ++chunk) {
        if (chunk + 1 < NCHUNKS) loadB(chunk + 1);   // hide under MFMA+epilogue

        f32x4 acc[2][4];
        #pragma unroll
        for (int mt = 0; mt < 2; ++mt)
            #pragma unroll
            for (int nt = 0; nt < 4; ++nt)
                acc[mt][nt] = (f32x4){0.f, 0.f, 0.f, 0.f};

        #pragma unroll
        for (int kk = 0; kk < 4; ++kk) {
            bf16x8 bfr[4];
            #pragma unroll
            for (int nt = 0; nt < 4; ++nt) {
                const int row = nt * 16 + fr;
                const int g = (kk * 4 + fq) ^ (row & 7);
                bfr[nt] = *(const bf16x8*)(&Bbuf[cur][row * KHALF + g * 8]);
            }
            #pragma unroll
            for (int mt = 0; mt < 2; ++mt)
                #pragma unroll
                for (int nt = 0; nt < 4; ++nt)
                    acc[mt][nt] = __builtin_amdgcn_mfma_f32_16x16x32_bf16(
                        af[mt][kk], bfr[nt], acc[mt][nt], 0, 0, 0);
        }

        // Epilogue: G[m,i] -> j = (m - i - 450) mod 900; combine equal-diagonal tiles
        const int base_mi = (m0 + wave * 32) - (chunk * NCHUNK) + 4 * fq - fr - PVAL;
        #pragma unroll
        for (int d = -3; d <= 1; ++d) {
            f32x4 comb = (f32x4){0.f, 0.f, 0.f, 0.f};
            #pragma unroll
            for (int mt = 0; mt < 2; ++mt) {
                const int nt = mt - d;
                if (nt >= 0 && nt < 4) comb += acc[mt][nt];
            }
            int j0 = (base_mi + 16 * d) % WW;
            if (j0 < 0) j0 += WW;
            #pragma unroll
            for (int r = 0; r < 4; ++r) {
                int j = j0 + r;
                if (j >= WW) j -= WW;
                unsafeAtomicAdd(&partial[j], comb[r]);   // native ds_add_f32
            }
        }

        if (chunk + 1 < NCHUNKS) writeB(cur ^ 1);
        __syncthreads();
        cur ^= 1;
    }

    for (int i = tid; i < WW; i += 256)
        unsafeAtomicAdd(&out[(size_t)b * WW + i], partial[i]);  // native global f32 add
}

extern "C" void kernel_launch(void* const* d_in, const int* in_sizes, int n_in,
                              void* d_out, int out_size, void* d_ws, size_t ws_size,
                              hipStream_t stream) {
    const float* x1 = (const float*)d_in[0];
    const float* x2 = (const float*)d_in[1];
    float* out = (float*)d_out;
    float* ws = (float*)d_ws;   // needs 320 KB: 256 KB partial sums + 64 KB inv

    hipMemsetAsync(d_out, 0, (size_t)out_size * sizeof(float), stream);
    nc_norm_partial<<<256, 256, 0, stream>>>(x1, x2, ws);
    nc_norm_finalize<<<64, 256, 0, stream>>>(ws);
    nc_corr<<<512, 256, 0, stream>>>(x1, x2, ws, out);
}